// Round 6
// baseline (958.850 us; speedup 1.0000x reference)
//
#include <hip/hip_runtime.h>
#include <hip/hip_bf16.h>

// 5-layer GCN: widths 128 -> 128/64/32/16/8, N=100000 nodes, E=1600000 edges.
// R5: fix compile — __builtin_nontemporal_load needs a native vector type,
//     not HIP_vector_type<float,4>; use ext_vector_type(4) alias for the
//     GEMM's streaming x load.
// R4: non-temporal loads for all streaming arrays (csr_src/src/dst/x-staging)
//     so the L2-resident g slice isn't evicted by stream traffic; aggr
//     restructured to full-node-per-thread with x4 unroll.
// R3: XCD-range-partitioned CSR build (no partial-line write amplification).
// R2: blocked g layout [f/8][N][8], slice-per-XCD L2-resident aggregation.
// R1: register-blocked fp32 GEMM (4x4 micro-tile, K-chunked LDS staging).

#define SCAN_B 1024

typedef float floatx4 __attribute__((ext_vector_type(4)));

// ---------------- ranged degree histogram ----------------
__global__ __launch_bounds__(256) void k_count_r(const int* __restrict__ dst,
                                                 int* __restrict__ deg, int E, int N) {
    const int r  = blockIdx.x % 8;
    const int lo = (int)((long long)r * N / 8);
    const int hi = (int)((long long)(r + 1) * N / 8);
    const int nb = gridDim.x / 8;
    const int jb = blockIdx.x / 8;
    const int stride = nb * 256;
    for (int e = jb * 256 + threadIdx.x; e < E; e += stride) {
        int d = __builtin_nontemporal_load(&dst[e]);
        if (d >= lo && d < hi) atomicAdd(&deg[d], 1);
    }
}

// ---------------- exclusive scan (3 kernels) ----------------
__global__ void k_scan_block(const int* __restrict__ deg, int* __restrict__ out,
                             int* __restrict__ sums, int n) {
    __shared__ int tmp[SCAN_B];
    int i = blockIdx.x * SCAN_B + threadIdx.x;
    int v = (i < n) ? deg[i] : 0;
    tmp[threadIdx.x] = v;
    __syncthreads();
    for (int off = 1; off < SCAN_B; off <<= 1) {
        int t = (threadIdx.x >= off) ? tmp[threadIdx.x - off] : 0;
        __syncthreads();
        tmp[threadIdx.x] += t;
        __syncthreads();
    }
    if (i < n) out[i] = tmp[threadIdx.x] - v;   // exclusive within block
    if (threadIdx.x == SCAN_B - 1) sums[blockIdx.x] = tmp[threadIdx.x];
}

__global__ void k_scan_sums(int* __restrict__ sums, int nb) {
    __shared__ int tmp[128];
    int v = (threadIdx.x < nb) ? sums[threadIdx.x] : 0;
    tmp[threadIdx.x] = v;
    __syncthreads();
    for (int off = 1; off < 128; off <<= 1) {
        int t = (threadIdx.x >= off) ? tmp[threadIdx.x - off] : 0;
        __syncthreads();
        tmp[threadIdx.x] += t;
        __syncthreads();
    }
    if (threadIdx.x < nb) sums[threadIdx.x] = tmp[threadIdx.x] - v;  // exclusive
}

__global__ void k_finalize(int* __restrict__ offsets, const int* __restrict__ sums,
                           const int* __restrict__ deg, int* __restrict__ cursor,
                           float* __restrict__ dinv, int n, int E) {
    int i = blockIdx.x * blockDim.x + threadIdx.x;
    if (i < n) {
        int off = offsets[i] + sums[i / SCAN_B];
        offsets[i] = off;
        cursor[i]  = off;
        dinv[i]    = rsqrtf((float)(deg[i] + 1));   // +1 self loop
    }
    if (i == 0) offsets[n] = E;
}

// ---------------- ranged CSR bucket fill ----------------
__global__ __launch_bounds__(256) void k_fill_r(const int* __restrict__ src,
                                                const int* __restrict__ dst,
                                                int* __restrict__ cursor,
                                                int* __restrict__ csr_src, int E, int N) {
    const int r  = blockIdx.x % 8;
    const int lo = (int)((long long)r * N / 8);
    const int hi = (int)((long long)(r + 1) * N / 8);
    const int nb = gridDim.x / 8;
    const int jb = blockIdx.x / 8;
    const int stride = nb * 256;
    for (int e = jb * 256 + threadIdx.x; e < E; e += stride) {
        int d = __builtin_nontemporal_load(&dst[e]);
        if (d >= lo && d < hi) {
            int pos = atomicAdd(&cursor[d], 1);
            csr_src[pos] = __builtin_nontemporal_load(&src[e]);
        }
    }
}

// ---------------- register-blocked GEMM ----------------
// g_b[fo/8][n][8] = dinv[n] * sum_k x[n,k] * W[k,fo]   (blocked output)
// BIN: input x is blocked [fi/8][n][8]; else row-major [n][FIN].
template <int FIN, int FOUT, bool BIN>
__global__ __launch_bounds__(256) void k_gemm(const float* __restrict__ x,
                                              const float* __restrict__ W,
                                              const float* __restrict__ dinv,
                                              float* __restrict__ g, int n) {
    constexpr int NFG = FOUT / 4;
    constexpr int M   = 4 * (256 / NFG);
    constexpr int KC  = (FIN < 32) ? FIN : 32;
    constexpr int MP  = M + 4;
    __shared__ float Wl[KC * FOUT];
    __shared__ float xt[KC * MP];

    const int tid      = threadIdx.x;
    const int fo_group = tid % NFG;
    const int m_group  = tid / NFG;
    const int m0       = blockIdx.x * M;
    const floatx4* x4  = reinterpret_cast<const floatx4*>(x);

    float acc[4][4];
#pragma unroll
    for (int i = 0; i < 4; ++i)
#pragma unroll
        for (int j = 0; j < 4; ++j) acc[i][j] = 0.f;

    for (int kc0 = 0; kc0 < FIN; kc0 += KC) {
        __syncthreads();
        for (int i = tid; i < KC * FOUT; i += 256)
            Wl[i] = W[(kc0 + i / FOUT) * FOUT + (i % FOUT)];
        constexpr int SLOTS = KC / 4;           // float4 slots per node per chunk
        for (int s = tid; s < M * SLOTS; s += 256) {
            int ml    = s / SLOTS;
            int slot  = s % SLOTS;
            int gslot = kc0 / 4 + slot;
            int gn    = m0 + ml;
            floatx4 v = (floatx4)(0.f);
            if (gn < n) {
                size_t idx = BIN ? (((size_t)(gslot >> 1) * n + gn) * 2 + (gslot & 1))
                                 : ((size_t)gn * (FIN / 4) + gslot);
                v = __builtin_nontemporal_load(&x4[idx]);
            }
            xt[(slot * 4 + 0) * MP + ml] = v.x;
            xt[(slot * 4 + 1) * MP + ml] = v.y;
            xt[(slot * 4 + 2) * MP + ml] = v.z;
            xt[(slot * 4 + 3) * MP + ml] = v.w;
        }
        __syncthreads();
#pragma unroll
        for (int k = 0; k < KC; ++k) {
            float4 xv = *reinterpret_cast<const float4*>(&xt[k * MP + m_group * 4]);
            float4 wv = *reinterpret_cast<const float4*>(&Wl[k * FOUT + fo_group * 4]);
            const float xs[4] = {xv.x, xv.y, xv.z, xv.w};
            const float ws[4] = {wv.x, wv.y, wv.z, wv.w};
#pragma unroll
            for (int i = 0; i < 4; ++i)
#pragma unroll
                for (int j = 0; j < 4; ++j) acc[i][j] += xs[i] * ws[j];
        }
    }

    float4* g4 = reinterpret_cast<float4*>(g);
#pragma unroll
    for (int i = 0; i < 4; ++i) {
        int gn = m0 + m_group * 4 + i;
        if (gn < n) {
            float d = dinv[gn];
            float4 o = make_float4(acc[i][0] * d, acc[i][1] * d, acc[i][2] * d, acc[i][3] * d);
            g4[((size_t)(fo_group >> 1) * n + gn) * 2 + (fo_group & 1)] = o;
        }
    }
}

// ---------------- sliced CSR aggregation + bias + relu ----------------
// One slice = 8 features = 3.2 MB (N=100k) -> fits per-XCD L2.
// slice = blockIdx.x % nsl: round-robin block->XCD gives slice<->XCD affinity.
// One thread per node (full 8-feature slice, 2x float4); edge loop x4 unroll
// -> 8 outstanding 16B gathers. csr_src read non-temporally (evict-first) so
// the gather slice stays L2-resident.
__global__ __launch_bounds__(256) void k_aggr_s(const float4* __restrict__ gb,
                                                const int* __restrict__ offsets,
                                                const int* __restrict__ csr_src,
                                                const float* __restrict__ dinv,
                                                const float* __restrict__ bias,
                                                float4* __restrict__ outb,
                                                int n, int nsl, int slice_base) {
    const int sl    = blockIdx.x % nsl;
    const int nb    = blockIdx.x / nsl;
    const int slice = slice_base + sl;
    const int node  = nb * 256 + threadIdx.x;
    if (node >= n) return;

    const float4* gs = gb + (size_t)slice * n * 2;
    float4 aA = gs[node * 2 + 0];                 // self-loop term, lo half
    float4 bA = gs[node * 2 + 1];                 // hi half
    float4 aB = make_float4(0.f, 0.f, 0.f, 0.f);
    float4 bB = make_float4(0.f, 0.f, 0.f, 0.f);

    int e = offsets[node];
    const int e1 = offsets[node + 1];
    for (; e + 3 < e1; e += 4) {
        int s0 = __builtin_nontemporal_load(&csr_src[e]);
        int s1 = __builtin_nontemporal_load(&csr_src[e + 1]);
        int s2 = __builtin_nontemporal_load(&csr_src[e + 2]);
        int s3 = __builtin_nontemporal_load(&csr_src[e + 3]);
        float4 v0 = gs[s0 * 2 + 0], w0 = gs[s0 * 2 + 1];
        float4 v1 = gs[s1 * 2 + 0], w1 = gs[s1 * 2 + 1];
        float4 v2 = gs[s2 * 2 + 0], w2 = gs[s2 * 2 + 1];
        float4 v3 = gs[s3 * 2 + 0], w3 = gs[s3 * 2 + 1];
        aA.x += v0.x; aA.y += v0.y; aA.z += v0.z; aA.w += v0.w;
        bA.x += w0.x; bA.y += w0.y; bA.z += w0.z; bA.w += w0.w;
        aB.x += v1.x; aB.y += v1.y; aB.z += v1.z; aB.w += v1.w;
        bB.x += w1.x; bB.y += w1.y; bB.z += w1.z; bB.w += w1.w;
        aA.x += v2.x; aA.y += v2.y; aA.z += v2.z; aA.w += v2.w;
        bA.x += w2.x; bA.y += w2.y; bA.z += w2.z; bA.w += w2.w;
        aB.x += v3.x; aB.y += v3.y; aB.z += v3.z; aB.w += v3.w;
        bB.x += w3.x; bB.y += w3.y; bB.z += w3.z; bB.w += w3.w;
    }
    for (; e < e1; ++e) {
        int s = __builtin_nontemporal_load(&csr_src[e]);
        float4 v = gs[s * 2 + 0], w = gs[s * 2 + 1];
        aA.x += v.x; aA.y += v.y; aA.z += v.z; aA.w += v.w;
        bA.x += w.x; bA.y += w.y; bA.z += w.z; bA.w += w.w;
    }
    aA.x += aB.x; aA.y += aB.y; aA.z += aB.z; aA.w += aB.w;
    bA.x += bB.x; bA.y += bB.y; bA.z += bB.z; bA.w += bB.w;

    const float d = dinv[node];
    const float* bf = bias + slice * 8;
    float4 r0, r1;
    r0.x = fmaxf(d * aA.x + bf[0], 0.f);
    r0.y = fmaxf(d * aA.y + bf[1], 0.f);
    r0.z = fmaxf(d * aA.z + bf[2], 0.f);
    r0.w = fmaxf(d * aA.w + bf[3], 0.f);
    r1.x = fmaxf(d * bA.x + bf[4], 0.f);
    r1.y = fmaxf(d * bA.y + bf[5], 0.f);
    r1.z = fmaxf(d * bA.z + bf[6], 0.f);
    r1.w = fmaxf(d * bA.w + bf[7], 0.f);
    outb[((size_t)slice * n + node) * 2 + 0] = r0;
    outb[((size_t)slice * n + node) * 2 + 1] = r1;
}

extern "C" void kernel_launch(void* const* d_in, const int* in_sizes, int n_in,
                              void* d_out, int out_size, void* d_ws, size_t ws_size,
                              hipStream_t stream) {
    const int N = in_sizes[0] / 128;
    const int E = in_sizes[1] / 2;

    const float* x   = (const float*)d_in[0];
    const int*   ei  = (const int*)d_in[1];
    const int*   src = ei;
    const int*   dst = ei + E;
    const float* W1 = (const float*)d_in[2],  *b1 = (const float*)d_in[3];
    const float* W2 = (const float*)d_in[4],  *b2 = (const float*)d_in[5];
    const float* W3 = (const float*)d_in[6],  *b3 = (const float*)d_in[7];
    const float* W4 = (const float*)d_in[8],  *b4 = (const float*)d_in[9];
    const float* W5 = (const float*)d_in[10], *b5 = (const float*)d_in[11];
    float* out = (float*)d_out;

    size_t off = 0;
    auto alloc = [&](size_t bytes) {
        void* p = (char*)d_ws + off;
        off += (bytes + 255) & ~(size_t)255;
        return p;
    };
    int*   deg     = (int*)alloc((size_t)N * 4);
    int*   offsets = (int*)alloc((size_t)(N + 1) * 4);
    int*   cursor  = (int*)alloc((size_t)N * 4);
    int*   sums    = (int*)alloc(128 * 4);
    float* dinv    = (float*)alloc((size_t)N * 4);
    int*   csr_src = (int*)alloc((size_t)E * 4);
    float* g       = (float*)alloc((size_t)N * 128 * 4);
    float* xbuf    = (float*)alloc((size_t)N * 128 * 4);

    (void)hipMemsetAsync(deg, 0, (size_t)N * 4, stream);

    const int TB = 256;
    int nb = (N + SCAN_B - 1) / SCAN_B;
    int nodeBlk = (N + 255) / 256;   // aggr: 256 nodes per block
    const int RG = 2048;             // ranged kernels: 256 blocks per dst-range

    k_count_r<<<RG, TB, 0, stream>>>(dst, deg, E, N);
    k_scan_block<<<nb, SCAN_B, 0, stream>>>(deg, offsets, sums, N);
    k_scan_sums<<<1, 128, 0, stream>>>(sums, nb);
    k_finalize<<<(N + TB - 1) / TB, TB, 0, stream>>>(offsets, sums, deg, cursor, dinv, N, E);
    k_fill_r<<<RG, TB, 0, stream>>>(src, dst, cursor, csr_src, E, N);

    const float4* g4  = (const float4*)g;
    float4*       xb4 = (float4*)xbuf;

    // Layer 1: 128 -> 128  (16 slices: 2 launches of 8 for XCD affinity)
    k_gemm<128, 128, false><<<(N + 31) / 32, TB, 0, stream>>>(x, W1, dinv, g, N);
    k_aggr_s<<<nodeBlk * 8, TB, 0, stream>>>(g4, offsets, csr_src, dinv, b1, xb4, N, 8, 0);
    k_aggr_s<<<nodeBlk * 8, TB, 0, stream>>>(g4, offsets, csr_src, dinv, b1, xb4, N, 8, 8);
    // Layer 2: 128 -> 64  (8 slices)
    k_gemm<128, 64, true><<<(N + 63) / 64, TB, 0, stream>>>(xbuf, W2, dinv, g, N);
    k_aggr_s<<<nodeBlk * 8, TB, 0, stream>>>(g4, offsets, csr_src, dinv, b2, xb4, N, 8, 0);
    // Layer 3: 64 -> 32  (4 slices)
    k_gemm<64, 32, true><<<(N + 127) / 128, TB, 0, stream>>>(xbuf, W3, dinv, g, N);
    k_aggr_s<<<nodeBlk * 4, TB, 0, stream>>>(g4, offsets, csr_src, dinv, b3, xb4, N, 4, 0);
    // Layer 4: 32 -> 16  (2 slices)
    k_gemm<32, 16, true><<<(N + 255) / 256, TB, 0, stream>>>(xbuf, W4, dinv, g, N);
    k_aggr_s<<<nodeBlk * 2, TB, 0, stream>>>(g4, offsets, csr_src, dinv, b4, xb4, N, 2, 0);
    // Layer 5: 16 -> 8  (1 slice; blocked F=8 == row-major -> write d_out)
    k_gemm<16, 8, true><<<(N + 511) / 512, TB, 0, stream>>>(xbuf, W5, dinv, g, N);
    k_aggr_s<<<nodeBlk * 1, TB, 0, stream>>>(g4, offsets, csr_src, dinv, b5, (float4*)out, N, 1, 0);
}

// Round 7
// 738.070 us; speedup vs baseline: 1.2991x; 1.2991x over previous
//
#include <hip/hip_runtime.h>
#include <hip/hip_bf16.h>

// 5-layer GCN: widths 128 -> 128/64/32/16/8, N=100000 nodes, E=1600000 edges.
// R6: REVERT R4's aggr regression (nt csr_src caused ~16x index-line refetch,
//     FETCH 137->175 MB, VALUBusy 11.5->4.2). Back to 2-threads-per-node,
//     regular csr_src loads; NEW: software prefetch of next index quad to
//     break the index->gather dependency chain.
// R3: XCD-range-partitioned CSR build (no partial-line write amplification).
// R2: blocked g layout [f/8][N][8], slice-per-XCD L2-resident aggregation.
// R1: register-blocked fp32 GEMM (4x4 micro-tile, K-chunked LDS staging).

#define SCAN_B 1024

typedef float floatx4 __attribute__((ext_vector_type(4)));

// ---------------- ranged degree histogram ----------------
__global__ __launch_bounds__(256) void k_count_r(const int* __restrict__ dst,
                                                 int* __restrict__ deg, int E, int N) {
    const int r  = blockIdx.x % 8;
    const int lo = (int)((long long)r * N / 8);
    const int hi = (int)((long long)(r + 1) * N / 8);
    const int nb = gridDim.x / 8;
    const int jb = blockIdx.x / 8;
    const int stride = nb * 256;
    for (int e = jb * 256 + threadIdx.x; e < E; e += stride) {
        int d = __builtin_nontemporal_load(&dst[e]);
        if (d >= lo && d < hi) atomicAdd(&deg[d], 1);
    }
}

// ---------------- exclusive scan (3 kernels) ----------------
__global__ void k_scan_block(const int* __restrict__ deg, int* __restrict__ out,
                             int* __restrict__ sums, int n) {
    __shared__ int tmp[SCAN_B];
    int i = blockIdx.x * SCAN_B + threadIdx.x;
    int v = (i < n) ? deg[i] : 0;
    tmp[threadIdx.x] = v;
    __syncthreads();
    for (int off = 1; off < SCAN_B; off <<= 1) {
        int t = (threadIdx.x >= off) ? tmp[threadIdx.x - off] : 0;
        __syncthreads();
        tmp[threadIdx.x] += t;
        __syncthreads();
    }
    if (i < n) out[i] = tmp[threadIdx.x] - v;   // exclusive within block
    if (threadIdx.x == SCAN_B - 1) sums[blockIdx.x] = tmp[threadIdx.x];
}

__global__ void k_scan_sums(int* __restrict__ sums, int nb) {
    __shared__ int tmp[128];
    int v = (threadIdx.x < nb) ? sums[threadIdx.x] : 0;
    tmp[threadIdx.x] = v;
    __syncthreads();
    for (int off = 1; off < 128; off <<= 1) {
        int t = (threadIdx.x >= off) ? tmp[threadIdx.x - off] : 0;
        __syncthreads();
        tmp[threadIdx.x] += t;
        __syncthreads();
    }
    if (threadIdx.x < nb) sums[threadIdx.x] = tmp[threadIdx.x] - v;  // exclusive
}

__global__ void k_finalize(int* __restrict__ offsets, const int* __restrict__ sums,
                           const int* __restrict__ deg, int* __restrict__ cursor,
                           float* __restrict__ dinv, int n, int E) {
    int i = blockIdx.x * blockDim.x + threadIdx.x;
    if (i < n) {
        int off = offsets[i] + sums[i / SCAN_B];
        offsets[i] = off;
        cursor[i]  = off;
        dinv[i]    = rsqrtf((float)(deg[i] + 1));   // +1 self loop
    }
    if (i == 0) offsets[n] = E;
}

// ---------------- ranged CSR bucket fill ----------------
__global__ __launch_bounds__(256) void k_fill_r(const int* __restrict__ src,
                                                const int* __restrict__ dst,
                                                int* __restrict__ cursor,
                                                int* __restrict__ csr_src, int E, int N) {
    const int r  = blockIdx.x % 8;
    const int lo = (int)((long long)r * N / 8);
    const int hi = (int)((long long)(r + 1) * N / 8);
    const int nb = gridDim.x / 8;
    const int jb = blockIdx.x / 8;
    const int stride = nb * 256;
    for (int e = jb * 256 + threadIdx.x; e < E; e += stride) {
        int d = __builtin_nontemporal_load(&dst[e]);
        if (d >= lo && d < hi) {
            int pos = atomicAdd(&cursor[d], 1);
            csr_src[pos] = __builtin_nontemporal_load(&src[e]);
        }
    }
}

// ---------------- register-blocked GEMM ----------------
// g_b[fo/8][n][8] = dinv[n] * sum_k x[n,k] * W[k,fo]   (blocked output)
// BIN: input x is blocked [fi/8][n][8]; else row-major [n][FIN].
template <int FIN, int FOUT, bool BIN>
__global__ __launch_bounds__(256) void k_gemm(const float* __restrict__ x,
                                              const float* __restrict__ W,
                                              const float* __restrict__ dinv,
                                              float* __restrict__ g, int n) {
    constexpr int NFG = FOUT / 4;
    constexpr int M   = 4 * (256 / NFG);
    constexpr int KC  = (FIN < 32) ? FIN : 32;
    constexpr int MP  = M + 4;
    __shared__ float Wl[KC * FOUT];
    __shared__ float xt[KC * MP];

    const int tid      = threadIdx.x;
    const int fo_group = tid % NFG;
    const int m_group  = tid / NFG;
    const int m0       = blockIdx.x * M;
    const floatx4* x4  = reinterpret_cast<const floatx4*>(x);

    float acc[4][4];
#pragma unroll
    for (int i = 0; i < 4; ++i)
#pragma unroll
        for (int j = 0; j < 4; ++j) acc[i][j] = 0.f;

    for (int kc0 = 0; kc0 < FIN; kc0 += KC) {
        __syncthreads();
        for (int i = tid; i < KC * FOUT; i += 256)
            Wl[i] = W[(kc0 + i / FOUT) * FOUT + (i % FOUT)];
        constexpr int SLOTS = KC / 4;           // float4 slots per node per chunk
        for (int s = tid; s < M * SLOTS; s += 256) {
            int ml    = s / SLOTS;
            int slot  = s % SLOTS;
            int gslot = kc0 / 4 + slot;
            int gn    = m0 + ml;
            floatx4 v = (floatx4)(0.f);
            if (gn < n) {
                size_t idx = BIN ? (((size_t)(gslot >> 1) * n + gn) * 2 + (gslot & 1))
                                 : ((size_t)gn * (FIN / 4) + gslot);
                v = __builtin_nontemporal_load(&x4[idx]);
            }
            xt[(slot * 4 + 0) * MP + ml] = v.x;
            xt[(slot * 4 + 1) * MP + ml] = v.y;
            xt[(slot * 4 + 2) * MP + ml] = v.z;
            xt[(slot * 4 + 3) * MP + ml] = v.w;
        }
        __syncthreads();
#pragma unroll
        for (int k = 0; k < KC; ++k) {
            float4 xv = *reinterpret_cast<const float4*>(&xt[k * MP + m_group * 4]);
            float4 wv = *reinterpret_cast<const float4*>(&Wl[k * FOUT + fo_group * 4]);
            const float xs[4] = {xv.x, xv.y, xv.z, xv.w};
            const float ws[4] = {wv.x, wv.y, wv.z, wv.w};
#pragma unroll
            for (int i = 0; i < 4; ++i)
#pragma unroll
                for (int j = 0; j < 4; ++j) acc[i][j] += xs[i] * ws[j];
        }
    }

    float4* g4 = reinterpret_cast<float4*>(g);
#pragma unroll
    for (int i = 0; i < 4; ++i) {
        int gn = m0 + m_group * 4 + i;
        if (gn < n) {
            float d = dinv[gn];
            float4 o = make_float4(acc[i][0] * d, acc[i][1] * d, acc[i][2] * d, acc[i][3] * d);
            g4[((size_t)(fo_group >> 1) * n + gn) * 2 + (fo_group & 1)] = o;
        }
    }
}

// ---------------- sliced CSR aggregation + bias + relu ----------------
// One slice = 8 features = 3.2 MB (N=100k) -> fits per-XCD L2.
// slice = blockIdx.x % nsl: round-robin block->XCD gives slice<->XCD affinity.
// 2 threads per node (half-slice float4 each); edge loop x4 unroll with
// next-quad index prefetch (breaks index->gather dependency chain).
__global__ __launch_bounds__(256) void k_aggr_s(const float4* __restrict__ gb,
                                                const int* __restrict__ offsets,
                                                const int* __restrict__ csr_src,
                                                const float* __restrict__ dinv,
                                                const float* __restrict__ bias,
                                                float4* __restrict__ outb,
                                                int n, int nsl, int slice_base) {
    const int sl    = blockIdx.x % nsl;
    const int nb    = blockIdx.x / nsl;
    const int slice = slice_base + sl;
    const int node  = nb * 128 + (threadIdx.x >> 1);
    const int h     = threadIdx.x & 1;
    if (node >= n) return;

    const float4* gs = gb + (size_t)slice * n * 2;
    float4 a0 = gs[node * 2 + h];                 // self-loop term
    float4 a1 = make_float4(0.f, 0.f, 0.f, 0.f);
    float4 a2 = a1, a3 = a1;

    int e = offsets[node];
    const int e1 = offsets[node + 1];

    int s0 = 0, s1 = 0, s2 = 0, s3 = 0;
    if (e + 3 < e1) {                              // preload first quad
        s0 = csr_src[e]; s1 = csr_src[e + 1]; s2 = csr_src[e + 2]; s3 = csr_src[e + 3];
    }
    for (; e + 7 < e1; e += 4) {
        // prefetch next quad before using current gathers
        int t0 = csr_src[e + 4], t1 = csr_src[e + 5], t2 = csr_src[e + 6], t3 = csr_src[e + 7];
        float4 v0 = gs[s0 * 2 + h];
        float4 v1 = gs[s1 * 2 + h];
        float4 v2 = gs[s2 * 2 + h];
        float4 v3 = gs[s3 * 2 + h];
        a0.x += v0.x; a0.y += v0.y; a0.z += v0.z; a0.w += v0.w;
        a1.x += v1.x; a1.y += v1.y; a1.z += v1.z; a1.w += v1.w;
        a2.x += v2.x; a2.y += v2.y; a2.z += v2.z; a2.w += v2.w;
        a3.x += v3.x; a3.y += v3.y; a3.z += v3.z; a3.w += v3.w;
        s0 = t0; s1 = t1; s2 = t2; s3 = t3;
    }
    if (e + 3 < e1) {                              // last preloaded quad
        float4 v0 = gs[s0 * 2 + h];
        float4 v1 = gs[s1 * 2 + h];
        float4 v2 = gs[s2 * 2 + h];
        float4 v3 = gs[s3 * 2 + h];
        a0.x += v0.x; a0.y += v0.y; a0.z += v0.z; a0.w += v0.w;
        a1.x += v1.x; a1.y += v1.y; a1.z += v1.z; a1.w += v1.w;
        a2.x += v2.x; a2.y += v2.y; a2.z += v2.z; a2.w += v2.w;
        a3.x += v3.x; a3.y += v3.y; a3.z += v3.z; a3.w += v3.w;
        e += 4;
    }
    for (; e < e1; ++e) {
        float4 v = gs[csr_src[e] * 2 + h];
        a0.x += v.x; a0.y += v.y; a0.z += v.z; a0.w += v.w;
    }
    a0.x += a1.x + a2.x + a3.x;
    a0.y += a1.y + a2.y + a3.y;
    a0.z += a1.z + a2.z + a3.z;
    a0.w += a1.w + a2.w + a3.w;

    const float d = dinv[node];
    const float* bf = bias + slice * 8 + h * 4;
    float4 r;
    r.x = fmaxf(d * a0.x + bf[0], 0.f);
    r.y = fmaxf(d * a0.y + bf[1], 0.f);
    r.z = fmaxf(d * a0.z + bf[2], 0.f);
    r.w = fmaxf(d * a0.w + bf[3], 0.f);
    outb[((size_t)slice * n + node) * 2 + h] = r;
}

extern "C" void kernel_launch(void* const* d_in, const int* in_sizes, int n_in,
                              void* d_out, int out_size, void* d_ws, size_t ws_size,
                              hipStream_t stream) {
    const int N = in_sizes[0] / 128;
    const int E = in_sizes[1] / 2;

    const float* x   = (const float*)d_in[0];
    const int*   ei  = (const int*)d_in[1];
    const int*   src = ei;
    const int*   dst = ei + E;
    const float* W1 = (const float*)d_in[2],  *b1 = (const float*)d_in[3];
    const float* W2 = (const float*)d_in[4],  *b2 = (const float*)d_in[5];
    const float* W3 = (const float*)d_in[6],  *b3 = (const float*)d_in[7];
    const float* W4 = (const float*)d_in[8],  *b4 = (const float*)d_in[9];
    const float* W5 = (const float*)d_in[10], *b5 = (const float*)d_in[11];
    float* out = (float*)d_out;

    size_t off = 0;
    auto alloc = [&](size_t bytes) {
        void* p = (char*)d_ws + off;
        off += (bytes + 255) & ~(size_t)255;
        return p;
    };
    int*   deg     = (int*)alloc((size_t)N * 4);
    int*   offsets = (int*)alloc((size_t)(N + 1) * 4);
    int*   cursor  = (int*)alloc((size_t)N * 4);
    int*   sums    = (int*)alloc(128 * 4);
    float* dinv    = (float*)alloc((size_t)N * 4);
    int*   csr_src = (int*)alloc((size_t)E * 4);
    float* g       = (float*)alloc((size_t)N * 128 * 4);
    float* xbuf    = (float*)alloc((size_t)N * 128 * 4);

    (void)hipMemsetAsync(deg, 0, (size_t)N * 4, stream);

    const int TB = 256;
    int nb = (N + SCAN_B - 1) / SCAN_B;
    int nodeBlk = (N + 127) / 128;   // aggr: 128 nodes per block
    const int RG = 2048;             // ranged kernels: 256 blocks per dst-range

    k_count_r<<<RG, TB, 0, stream>>>(dst, deg, E, N);
    k_scan_block<<<nb, SCAN_B, 0, stream>>>(deg, offsets, sums, N);
    k_scan_sums<<<1, 128, 0, stream>>>(sums, nb);
    k_finalize<<<(N + TB - 1) / TB, TB, 0, stream>>>(offsets, sums, deg, cursor, dinv, N, E);
    k_fill_r<<<RG, TB, 0, stream>>>(src, dst, cursor, csr_src, E, N);

    const float4* g4  = (const float4*)g;
    float4*       xb4 = (float4*)xbuf;

    // Layer 1: 128 -> 128  (16 slices: 2 launches of 8 for XCD affinity)
    k_gemm<128, 128, false><<<(N + 31) / 32, TB, 0, stream>>>(x, W1, dinv, g, N);
    k_aggr_s<<<nodeBlk * 8, TB, 0, stream>>>(g4, offsets, csr_src, dinv, b1, xb4, N, 8, 0);
    k_aggr_s<<<nodeBlk * 8, TB, 0, stream>>>(g4, offsets, csr_src, dinv, b1, xb4, N, 8, 8);
    // Layer 2: 128 -> 64  (8 slices)
    k_gemm<128, 64, true><<<(N + 63) / 64, TB, 0, stream>>>(xbuf, W2, dinv, g, N);
    k_aggr_s<<<nodeBlk * 8, TB, 0, stream>>>(g4, offsets, csr_src, dinv, b2, xb4, N, 8, 0);
    // Layer 3: 64 -> 32  (4 slices)
    k_gemm<64, 32, true><<<(N + 127) / 128, TB, 0, stream>>>(xbuf, W3, dinv, g, N);
    k_aggr_s<<<nodeBlk * 4, TB, 0, stream>>>(g4, offsets, csr_src, dinv, b3, xb4, N, 4, 0);
    // Layer 4: 32 -> 16  (2 slices)
    k_gemm<32, 16, true><<<(N + 255) / 256, TB, 0, stream>>>(xbuf, W4, dinv, g, N);
    k_aggr_s<<<nodeBlk * 2, TB, 0, stream>>>(g4, offsets, csr_src, dinv, b4, xb4, N, 2, 0);
    // Layer 5: 16 -> 8  (1 slice; blocked F=8 == row-major -> write d_out)
    k_gemm<16, 8, true><<<(N + 511) / 512, TB, 0, stream>>>(xbuf, W5, dinv, g, N);
    k_aggr_s<<<nodeBlk * 1, TB, 0, stream>>>(g4, offsets, csr_src, dinv, b5, (float4*)out, N, 1, 0);
}